// Round 8
// baseline (129.889 us; speedup 1.0000x reference)
//
#include <hip/hip_runtime.h>

#define HEADS 4
#define NN 256
#define DW 32
#define LOG2E 1.4426950408889634f
// (m-1)*MASKBIG added in log2 domain: m=0 -> -1.44e9 -> exp2() == 0.0f
#define MASKBIG 1.442695e9f

typedef __bf16 bf16x8 __attribute__((ext_vector_type(8)));
typedef float f32x4 __attribute__((ext_vector_type(4)));
typedef float f32x16 __attribute__((ext_vector_type(16)));
typedef unsigned int u32x4 __attribute__((ext_vector_type(4)));
typedef unsigned short ushort4v __attribute__((ext_vector_type(4)));

static __device__ __forceinline__ ushort f2bf(float f) {
  __bf16 h = (__bf16)f;
  ushort r;
  __builtin_memcpy(&r, &h, 2);
  return r;
}

static __device__ __forceinline__ unsigned cvt_pk_bf16(float lo, float hi) {
  unsigned r;
  asm("v_cvt_pk_bf16_f32 %0, %1, %2" : "=v"(r) : "v"(lo), "v"(hi));
  return r;
}

// ---------------------------------------------------------------------------
// Triangle bias in wave-coalesced MFMA-C tile layout, pre-scaled by log2(e):
//   bias2[((((h*8+kb)*4+g)*2+hi)*256 + q)*4 + e] = (x[q,k,:].Wb[h]+bb[h])*LOG2E
// with k = kb*32 + 8*g + 4*hi + e (the 32x32x16 C/D row index r = 4g+e).
// One block per q-row; x[q,:,:] staged to LDS with per-instruction-coalesced
// dwordx4 loads; thread t owns key k=t.
// ---------------------------------------------------------------------------
__global__ __launch_bounds__(256) void bias_kernel(
    const float* __restrict__ x, const float* __restrict__ Wb,
    const float* __restrict__ bb, float* __restrict__ bias2) {
  __shared__ float xs[NN * 36];  // [k][36] pad-36: b128-aligned rows

  const int q = blockIdx.x;
  const int t = threadIdx.x;

  const float* xr = x + q * (NN * DW);
#pragma unroll
  for (int cc = 0; cc < 8; ++cc) {
    const int f = (cc * 256 + t) * 4;  // flat dword index
    const float4 v = *reinterpret_cast<const float4*>(xr + f);
    const int k = f >> 5;
    const int d = f & 31;
    *reinterpret_cast<float4*>(&xs[k * 36 + d]) = v;
  }
  __syncthreads();

  float xv[DW];
#pragma unroll
  for (int c = 0; c < 8; ++c) {
    const float4 v = *reinterpret_cast<const float4*>(&xs[t * 36 + c * 4]);
    xv[c * 4 + 0] = v.x; xv[c * 4 + 1] = v.y;
    xv[c * 4 + 2] = v.z; xv[c * 4 + 3] = v.w;
  }

  const int kb = t >> 5;
  const int c2 = t & 31;
  const int e = c2 & 3;
  const int hi = (c2 >> 2) & 1;
  const int g = c2 >> 3;

#pragma unroll
  for (int h = 0; h < HEADS; ++h) {
    float a0 = 0.f, a1 = 0.f;
#pragma unroll
    for (int d = 0; d < DW; d += 2) {
      a0 += xv[d] * Wb[h * DW + d];        // Wb uniform -> s_loads
      a1 += xv[d + 1] * Wb[h * DW + d + 1];
    }
    bias2[((((h * 8 + kb) * 4 + g) * 2 + hi) * NN + q) * 4 + e] =
        (a0 + a1 + bb[h]) * LOG2E;
  }
}

// ---------------------------------------------------------------------------
// Fused QKV projection + attention, swapped-QK 32x32x16 MFMA structure.
// grid = 512: block = (i = bid>>1, head-pair hp = bid&1), 512 threads =
// 8 waves. Wave w: head hh = w>>2, q-band wb = w&3 (rows 64*wb..+63).
//
// Residency: __launch_bounds__(512,4) -> 128-reg cap, 2 blocks/CU exactly
// (LDS 77KB x2), 512 blocks / 256 CU = ONE round, no tail, 16 waves/CU.
// r7 failed because unbounded alloc (~150) silently halved residency; this
// version DIETS the live set to ~110 so the 128 cap is met without spills:
//   - key mask folded into the MFMA C operand in log2 domain
//     (mk[] holds (m-1)*1.44e9; cc = bias + mterm) -> no post-exp2 muls,
//     no long-lived mvv block;
//   - no bias double-buffer (bias loads at tile top; 4 waves/SIMD TLP +
//     the other qt chain cover L2 latency);
//   - prologue sequenced (Wq frags dead before Wk/Wv load).
//
// S^T = K·Q^T -> lane l holds q = l&31, 16 keys at (r&3)+8*(r>>2)+4*(l>>5).
// Softmax lane-local, exp2-direct. P -> PV A-frags in-register via
// cvt_pk_bf16 + v_permlane32_swap. O C-layout cols = d -> coalesced stores.
// ---------------------------------------------------------------------------
__global__ __launch_bounds__(512, 4) void attn_mfma(
    const float* __restrict__ x, const float* __restrict__ mask,
    const float* __restrict__ Wq, const float* __restrict__ bq,
    const float* __restrict__ Wk, const float* __restrict__ bk,
    const float* __restrict__ Wv, const float* __restrict__ bv,
    const float* __restrict__ bias2, float* __restrict__ out) {
  __shared__ __align__(16) ushort Kq[2][NN][40];
  __shared__ __align__(16) ushort Vt[2][DW][264];
  __shared__ __align__(16) float mk[NN];   // holds mterm, not raw mask
  __shared__ __align__(16) float Ls[2][NN];

  const int bid = blockIdx.x;
  const int i = bid >> 1;
  const int hp = bid & 1;
  const int t = threadIdx.x;
  const int w = t >> 6;
  const int hh = w >> 2;        // head within pair
  const int h = hp * 2 + hh;    // global head
  const int wb = w & 3;         // q band
  const int l = t & 63;
  const int lo5 = l & 31;
  const int hi = l >> 5;
  const int lr = l & 15;
  const int lq = l >> 4;
  const int rowbase = wb * 64;
  const float scale = 0.17677669529663687f * LOG2E;  // log2e/sqrt(32)

  // ---- x A-fragments for this wave's 64 rows (reused for Q,K,V) ----
  bf16x8 af[4];
#pragma unroll
  for (int rt = 0; rt < 4; ++rt) {
    const float* xr = x + (i * NN + rowbase + rt * 16 + lr) * DW + lq * 8;
#pragma unroll
    for (int jj = 0; jj < 8; ++jj) af[rt][jj] = (__bf16)xr[jj];
  }

  // ---- Q phase: Wq frags -> project -> stage into Kq[hh] (own band) ----
  {
    bf16x8 wf[2];
#pragma unroll
    for (int nt = 0; nt < 2; ++nt) {
      const float* rq = Wq + (h * DW + nt * 16 + lr) * DW + lq * 8;
#pragma unroll
      for (int jj = 0; jj < 8; ++jj) wf[nt][jj] = (__bf16)rq[jj];
    }
#pragma unroll
    for (int rt = 0; rt < 4; ++rt) {
#pragma unroll
      for (int nt = 0; nt < 2; ++nt) {
        const int dd = nt * 16 + lr;
        f32x4 z = {0.f, 0.f, 0.f, 0.f};
        f32x4 cq = __builtin_amdgcn_mfma_f32_16x16x32_bf16(af[rt], wf[nt], z, 0, 0, 0);
        const float bqv = bq[h * DW + dd];
#pragma unroll
        for (int j = 0; j < 4; ++j)
          Kq[hh][rowbase + rt * 16 + lq * 4 + j][dd] =
              f2bf((cq[j] + bqv) * scale);
      }
    }
  }
  // own-wave write->read: compiler inserts lgkmcnt wait; no barrier needed
  bf16x8 qb[2][2];
#pragma unroll
  for (int qt = 0; qt < 2; ++qt)
#pragma unroll
    for (int dh = 0; dh < 2; ++dh)
      qb[qt][dh] =
          *(const bf16x8*)&Kq[hh][rowbase + qt * 32 + lo5][dh * 16 + 8 * hi];

  // ---- K+V phase: overwrite own band with K; stage V transposed ----
  {
    bf16x8 wfk[2], wfv[2];
#pragma unroll
    for (int nt = 0; nt < 2; ++nt) {
      const float* rk = Wk + (h * DW + nt * 16 + lr) * DW + lq * 8;
      const float* rv = Wv + (h * DW + nt * 16 + lr) * DW + lq * 8;
#pragma unroll
      for (int jj = 0; jj < 8; ++jj) {
        wfk[nt][jj] = (__bf16)rk[jj];
        wfv[nt][jj] = (__bf16)rv[jj];
      }
    }
#pragma unroll
    for (int rt = 0; rt < 4; ++rt) {
#pragma unroll
      for (int nt = 0; nt < 2; ++nt) {
        const int dd = nt * 16 + lr;
        f32x4 z = {0.f, 0.f, 0.f, 0.f};
        f32x4 ck = __builtin_amdgcn_mfma_f32_16x16x32_bf16(af[rt], wfk[nt], z, 0, 0, 0);
        f32x4 cv = __builtin_amdgcn_mfma_f32_16x16x32_bf16(af[rt], wfv[nt], z, 0, 0, 0);
        const float bkv = bk[h * DW + dd];
        const float bvv = bv[h * DW + dd];
#pragma unroll
        for (int j = 0; j < 4; ++j)
          Kq[hh][rowbase + rt * 16 + lq * 4 + j][dd] = f2bf(ck[j] + bkv);
        ushort4v v4;
#pragma unroll
        for (int j = 0; j < 4; ++j) v4[j] = f2bf(cv[j] + bvv);
        *(ushort4v*)&Vt[hh][dd][rowbase + rt * 16 + lq * 4] = v4;
      }
    }
  }
  // mask -> log2-domain mterm: 0 (keep) or -1.44e9 (masked -> exp2 == 0)
  if (t < NN) mk[t] = (mask[i * NN + t] - 1.0f) * MASKBIG;
  __syncthreads();  // single barrier: K/V/mterm visible to all waves

  // ---- main loop over 8 key-blocks of 32; no barriers inside ----
  f32x16 ot[2];
  float lsum[2] = {0.f, 0.f};
#pragma unroll
  for (int qt = 0; qt < 2; ++qt)
#pragma unroll
    for (int r = 0; r < 16; ++r) ot[qt][r] = 0.f;

  // bias2 per-(head,hi) base; per tile: 4 loads at 8KB stride, each
  // instruction = two fully-used 512B segments.
  const float* btl = bias2 + h * (8 * 4 * 2 * NN * 4) + hi * (NN * 4);

#pragma unroll 1
  for (int kb = 0; kb < 8; ++kb) {
    const int kbase = kb * 32;
    const bf16x8 ka0 = *(const bf16x8*)&Kq[hh][kbase + lo5][8 * hi];
    const bf16x8 ka1 = *(const bf16x8*)&Kq[hh][kbase + lo5][16 + 8 * hi];
    const bf16x8 va0 = *(const bf16x8*)&Vt[hh][lo5][kbase + 8 * hi];
    const bf16x8 va1 = *(const bf16x8*)&Vt[hh][lo5][kbase + 16 + 8 * hi];
    // mterm for this key block (broadcast LDS reads, shared by both qt)
    float4 mt4[4];
#pragma unroll
    for (int g = 0; g < 4; ++g)
      mt4[g] = *(const float4*)&mk[kbase + 4 * hi + 8 * g];

    // per-tile body (qt literal at each call -> fully static indexing)
    auto tile = [&](const int qt) {
      // C operand = bias + mterm (mask folded in log2 domain)
      f32x16 cc;
      {
        const float* p = btl + kb * (8 * NN * 4) + (rowbase + qt * 32 + lo5) * 4;
#pragma unroll
        for (int g = 0; g < 4; ++g) {
          const f32x4 v = *(const f32x4*)(p + g * (2 * NN * 4));
#pragma unroll
          for (int e = 0; e < 4; ++e)
            cc[g * 4 + e] = v[e] + (&mt4[g].x)[e];
        }
      }
      __builtin_amdgcn_s_setprio(1);
      f32x16 st = __builtin_amdgcn_mfma_f32_32x32x16_bf16(ka0, qb[qt][0], cc, 0, 0, 0);
      st = __builtin_amdgcn_mfma_f32_32x32x16_bf16(ka1, qb[qt][1], st, 0, 0, 0);
      __builtin_amdgcn_s_setprio(0);

      // softmax numerator in place; pairwise-tree partial sums
#pragma unroll
      for (int r = 0; r < 16; ++r) st[r] = __builtin_amdgcn_exp2f(st[r]);
      float s0 = (st[0] + st[1]) + (st[2] + st[3]);
      float s1 = (st[4] + st[5]) + (st[6] + st[7]);
      float s2 = (st[8] + st[9]) + (st[10] + st[11]);
      float s3 = (st[12] + st[13]) + (st[14] + st[15]);
      lsum[qt] += (s0 + s1) + (s2 + s3);

      // P -> A-fragments: cvt_pk pairs + permlane32_swap
#pragma unroll
      for (int half = 0; half < 2; ++half) {
        const int b0 = half * 8;
        unsigned w0, w1, w2, w3;
        {
          unsigned A = cvt_pk_bf16(st[b0 + 0], st[b0 + 1]);
          unsigned B = cvt_pk_bf16(st[b0 + 4], st[b0 + 5]);
          asm volatile("v_permlane32_swap_b32 %0, %1" : "+v"(A), "+v"(B));
          w0 = A; w2 = B;
        }
        {
          unsigned A = cvt_pk_bf16(st[b0 + 2], st[b0 + 3]);
          unsigned B = cvt_pk_bf16(st[b0 + 6], st[b0 + 7]);
          asm volatile("v_permlane32_swap_b32 %0, %1" : "+v"(A), "+v"(B));
          w1 = A; w3 = B;
        }
        u32x4 words = {w0, w1, w2, w3};
        const bf16x8 pf = __builtin_bit_cast(bf16x8, words);
        __builtin_amdgcn_s_setprio(1);
        ot[qt] = __builtin_amdgcn_mfma_f32_32x32x16_bf16(
            pf, half ? va1 : va0, ot[qt], 0, 0, 0);
        __builtin_amdgcn_s_setprio(0);
      }
    };

    tile(0);
    tile(1);
  }

  // ---- denominators: lane-local + cross-half add, broadcast via LDS ----
#pragma unroll
  for (int qt = 0; qt < 2; ++qt) {
    const float ls = lsum[qt] + __shfl_xor(lsum[qt], 32);
    Ls[hh][rowbase + qt * 32 + lo5] = 1.0f / ls;  // both halves same value
  }

  // ---- normalize + store (C-layout cols = d -> coalesced 128B segments) ----
#pragma unroll
  for (int qt = 0; qt < 2; ++qt)
#pragma unroll
    for (int r = 0; r < 16; ++r) {
      const int qp = (r & 3) + 8 * (r >> 2) + 4 * hi;
      const int qrow = rowbase + qt * 32 + qp;
      out[((i * NN + qrow) * HEADS + h) * DW + lo5] = ot[qt][r] * Ls[hh][qrow];
    }
}

extern "C" void kernel_launch(void* const* d_in, const int* in_sizes, int n_in,
                              void* d_out, int out_size, void* d_ws,
                              size_t ws_size, hipStream_t stream) {
  const float* x    = (const float*)d_in[0];
  const float* mask = (const float*)d_in[1];
  const float* Wq   = (const float*)d_in[2];
  const float* bq   = (const float*)d_in[3];
  const float* Wk   = (const float*)d_in[4];
  const float* bk   = (const float*)d_in[5];
  const float* Wv   = (const float*)d_in[6];
  const float* bv   = (const float*)d_in[7];
  const float* Wb   = (const float*)d_in[8];
  const float* bb   = (const float*)d_in[9];
  float* out = (float*)d_out;
  float* bias2 = (float*)d_ws;  // HEADS*8*4*2*256*4 floats = 1 MB

  bias_kernel<<<NN, 256, 0, stream>>>(x, Wb, bb, bias2);
  attn_mfma<<<NN * 2, 512, 0, stream>>>(x, mask, Wq, bq, Wk, bk, Wv, bv,
                                        bias2, out);
}

// Round 9
// 118.262 us; speedup vs baseline: 1.0983x; 1.0983x over previous
//
#include <hip/hip_runtime.h>

#define HEADS 4
#define NN 256
#define DW 32
#define LOG2E 1.4426950408889634f
// (m-1)*MASKBIG added in log2 domain: m=0 -> -1.44e9 -> exp2() == 0.0f
#define MASKBIG 1.442695e9f

typedef __bf16 bf16x8 __attribute__((ext_vector_type(8)));
typedef float f32x4 __attribute__((ext_vector_type(4)));
typedef float f32x16 __attribute__((ext_vector_type(16)));
typedef unsigned int u32x4 __attribute__((ext_vector_type(4)));
typedef unsigned short ushort4v __attribute__((ext_vector_type(4)));

static __device__ __forceinline__ ushort f2bf(float f) {
  __bf16 h = (__bf16)f;
  ushort r;
  __builtin_memcpy(&r, &h, 2);
  return r;
}

static __device__ __forceinline__ unsigned cvt_pk_bf16(float lo, float hi) {
  unsigned r;
  asm("v_cvt_pk_bf16_f32 %0, %1, %2" : "=v"(r) : "v"(lo), "v"(hi));
  return r;
}

// ---------------------------------------------------------------------------
// Triangle bias in wave-coalesced MFMA-C tile layout, pre-scaled by log2(e):
//   bias2[((((h*8+kb)*4+g)*2+hi)*256 + q)*4 + e] = (x[q,k,:].Wb[h]+bb[h])*LOG2E
// with k = kb*32 + 8*g + 4*hi + e (the 32x32x16 C/D row index r = 4g+e).
// One block per q-row; x[q,:,:] staged to LDS with per-instruction-coalesced
// dwordx4 loads; thread t owns key k=t.
// ---------------------------------------------------------------------------
__global__ __launch_bounds__(256) void bias_kernel(
    const float* __restrict__ x, const float* __restrict__ Wb,
    const float* __restrict__ bb, float* __restrict__ bias2) {
  __shared__ float xs[NN * 36];  // [k][36] pad-36: b128-aligned rows

  const int q = blockIdx.x;
  const int t = threadIdx.x;

  const float* xr = x + q * (NN * DW);
#pragma unroll
  for (int cc = 0; cc < 8; ++cc) {
    const int f = (cc * 256 + t) * 4;  // flat dword index
    const float4 v = *reinterpret_cast<const float4*>(xr + f);
    const int k = f >> 5;
    const int d = f & 31;
    *reinterpret_cast<float4*>(&xs[k * 36 + d]) = v;
  }
  __syncthreads();

  float xv[DW];
#pragma unroll
  for (int c = 0; c < 8; ++c) {
    const float4 v = *reinterpret_cast<const float4*>(&xs[t * 36 + c * 4]);
    xv[c * 4 + 0] = v.x; xv[c * 4 + 1] = v.y;
    xv[c * 4 + 2] = v.z; xv[c * 4 + 3] = v.w;
  }

  const int kb = t >> 5;
  const int c2 = t & 31;
  const int e = c2 & 3;
  const int hi = (c2 >> 2) & 1;
  const int g = c2 >> 3;

#pragma unroll
  for (int h = 0; h < HEADS; ++h) {
    float a0 = 0.f, a1 = 0.f;
#pragma unroll
    for (int d = 0; d < DW; d += 2) {
      a0 += xv[d] * Wb[h * DW + d];        // Wb uniform -> s_loads
      a1 += xv[d + 1] * Wb[h * DW + d + 1];
    }
    bias2[((((h * 8 + kb) * 4 + g) * 2 + hi) * NN + q) * 4 + e] =
        (a0 + a1 + bb[h]) * LOG2E;
  }
}

// ---------------------------------------------------------------------------
// Fused QKV projection + attention, swapped-QK 32x32x16 MFMA structure.
// grid = 1024, 256 threads (4 waves), __launch_bounds__(256,3): the twice-
// measured stable envelope (~170-reg cap incl AGPR, zero spill; min-arg 4
// spills 20-100MB to scratch -- r4, r8).
// Block (via bijective XCD swizzle, 1024 = 8x128): bid2 = (bid&7)*128 +
// bid>>3; i = bid2>>2, h = bid2&3 -> the 4 same-i blocks share an XCD L2.
// Wave w owns queries 64w..64w+63 as two 32-row tiles.
//
// S^T = K·Q^T -> lane l holds q = l&31, 16 keys at (r&3)+8*(r>>2)+4*(l>>5).
// Key mask folded into the MFMA C operand in log2 domain (mk[] = mterm).
// Softmax lane-local, exp2-direct. P -> PV A-frags via cvt_pk_bf16 +
// v_permlane32_swap. O C-layout cols = d -> coalesced stores.
//
// MAIN-LOOP INTERLEAVE (this round's change): the two qt-chains are fully
// independent; r6 ran them sequentially, so the in-order wave stalled on
// every link (bias vmcnt -> S-MFMA -> exp2 -> pack -> PV). Both chains are
// now issued phase-by-phase (S-MFMA0|S-MFMA1, exp0 under S1's latency,
// PV0 MFMAs under pack1's VALU) -> ~2x per-wave ILP at unchanged TLP.
// ---------------------------------------------------------------------------
__global__ __launch_bounds__(256, 3) void attn_mfma(
    const float* __restrict__ x, const float* __restrict__ mask,
    const float* __restrict__ Wq, const float* __restrict__ bq,
    const float* __restrict__ Wk, const float* __restrict__ bk,
    const float* __restrict__ Wv, const float* __restrict__ bv,
    const float* __restrict__ bias2, float* __restrict__ out) {
  __shared__ __align__(16) ushort Kq[NN][40];
  __shared__ __align__(16) ushort Vt[DW][264];
  __shared__ __align__(16) float mk[NN];   // holds mterm, not raw mask
  __shared__ __align__(16) float Ls[NN];

  const int bid = blockIdx.x;
  const int bid2 = ((bid & 7) << 7) | (bid >> 3);  // bijective XCD swizzle
  const int i = bid2 >> 2;
  const int h = bid2 & 3;
  const int t = threadIdx.x;
  const int w = t >> 6;
  const int l = t & 63;
  const int lo5 = l & 31;
  const int hi = l >> 5;
  const int lr = l & 15;
  const int lq = l >> 4;
  const int rowbase = w * 64;
  const float scale = 0.17677669529663687f * LOG2E;  // log2e/sqrt(32)

  // ---- x A-fragments for this wave's 64 rows (reused for Q,K,V) ----
  bf16x8 af[4];
#pragma unroll
  for (int rt = 0; rt < 4; ++rt) {
    const float* xr = x + (i * NN + rowbase + rt * 16 + lr) * DW + lq * 8;
#pragma unroll
    for (int jj = 0; jj < 8; ++jj) af[rt][jj] = (__bf16)xr[jj];
  }

  // ---- Q phase: Wq frags -> project -> stage into Kq (own band) ----
  {
    bf16x8 wf[2];
#pragma unroll
    for (int nt = 0; nt < 2; ++nt) {
      const float* rq = Wq + (h * DW + nt * 16 + lr) * DW + lq * 8;
#pragma unroll
      for (int jj = 0; jj < 8; ++jj) wf[nt][jj] = (__bf16)rq[jj];
    }
#pragma unroll
    for (int rt = 0; rt < 4; ++rt) {
#pragma unroll
      for (int nt = 0; nt < 2; ++nt) {
        const int dd = nt * 16 + lr;
        f32x4 z = {0.f, 0.f, 0.f, 0.f};
        f32x4 cq = __builtin_amdgcn_mfma_f32_16x16x32_bf16(af[rt], wf[nt], z, 0, 0, 0);
        const float bqv = bq[h * DW + dd];
#pragma unroll
        for (int j = 0; j < 4; ++j)
          Kq[rowbase + rt * 16 + lq * 4 + j][dd] = f2bf((cq[j] + bqv) * scale);
      }
    }
  }
  // own-wave write->read: compiler inserts lgkmcnt wait; no barrier needed
  bf16x8 qb[2][2];
#pragma unroll
  for (int qt = 0; qt < 2; ++qt)
#pragma unroll
    for (int dh = 0; dh < 2; ++dh)
      qb[qt][dh] =
          *(const bf16x8*)&Kq[rowbase + qt * 32 + lo5][dh * 16 + 8 * hi];

  // ---- K+V phase: overwrite own band with K; stage V transposed ----
  {
    bf16x8 wfk[2], wfv[2];
#pragma unroll
    for (int nt = 0; nt < 2; ++nt) {
      const float* rk = Wk + (h * DW + nt * 16 + lr) * DW + lq * 8;
      const float* rv = Wv + (h * DW + nt * 16 + lr) * DW + lq * 8;
#pragma unroll
      for (int jj = 0; jj < 8; ++jj) {
        wfk[nt][jj] = (__bf16)rk[jj];
        wfv[nt][jj] = (__bf16)rv[jj];
      }
    }
#pragma unroll
    for (int rt = 0; rt < 4; ++rt) {
#pragma unroll
      for (int nt = 0; nt < 2; ++nt) {
        const int dd = nt * 16 + lr;
        f32x4 z = {0.f, 0.f, 0.f, 0.f};
        f32x4 ck = __builtin_amdgcn_mfma_f32_16x16x32_bf16(af[rt], wfk[nt], z, 0, 0, 0);
        f32x4 cv = __builtin_amdgcn_mfma_f32_16x16x32_bf16(af[rt], wfv[nt], z, 0, 0, 0);
        const float bkv = bk[h * DW + dd];
        const float bvv = bv[h * DW + dd];
#pragma unroll
        for (int j = 0; j < 4; ++j)
          Kq[rowbase + rt * 16 + lq * 4 + j][dd] = f2bf(ck[j] + bkv);
        ushort4v v4;
#pragma unroll
        for (int j = 0; j < 4; ++j) v4[j] = f2bf(cv[j] + bvv);
        *(ushort4v*)&Vt[dd][rowbase + rt * 16 + lq * 4] = v4;
      }
    }
  }
  // mask -> log2-domain mterm: 0 (keep) or -1.44e9 (masked -> exp2 == 0)
  mk[t] = (mask[i * NN + t] - 1.0f) * MASKBIG;
  __syncthreads();  // single barrier: K/V/mterm visible to all waves

  // ---- main loop over 8 key-blocks of 32; both qt chains interleaved ----
  f32x16 ot0, ot1;
  float lsum0 = 0.f, lsum1 = 0.f;
#pragma unroll
  for (int r = 0; r < 16; ++r) { ot0[r] = 0.f; ot1[r] = 0.f; }

  // bias2 per-(head,hi) base; per tile: 4 loads at 8KB stride, each
  // instruction = two fully-used 512B segments across the wave.
  const float* btl = bias2 + h * (8 * 4 * 2 * NN * 4) + hi * (NN * 4);

  // prefetch bias for kb = 0, both qt
  f32x4 bc0[4], bc1[4];
  {
    const float* p0 = btl + (rowbase + lo5) * 4;
    const float* p1 = btl + (rowbase + 32 + lo5) * 4;
#pragma unroll
    for (int g = 0; g < 4; ++g) {
      bc0[g] = *(const f32x4*)(p0 + g * (2 * NN * 4));
      bc1[g] = *(const f32x4*)(p1 + g * (2 * NN * 4));
    }
  }

#pragma unroll 1
  for (int kb = 0; kb < 8; ++kb) {
    const int kbase = kb * 32;
    const bf16x8 ka0 = *(const bf16x8*)&Kq[kbase + lo5][8 * hi];
    const bf16x8 ka1 = *(const bf16x8*)&Kq[kbase + lo5][16 + 8 * hi];
    const bf16x8 va0 = *(const bf16x8*)&Vt[lo5][kbase + 8 * hi];
    const bf16x8 va1 = *(const bf16x8*)&Vt[lo5][kbase + 16 + 8 * hi];
    float4 mt4[4];
#pragma unroll
    for (int g = 0; g < 4; ++g)
      mt4[g] = *(const float4*)&mk[kbase + 4 * hi + 8 * g];

    // prefetch bias for kb+1 (wrapped; unused values on last iter)
    f32x4 bn0[4], bn1[4];
    {
      const int kbn = (kb + 1) & 7;
      const float* p0 = btl + kbn * (8 * NN * 4) + (rowbase + lo5) * 4;
      const float* p1 = btl + kbn * (8 * NN * 4) + (rowbase + 32 + lo5) * 4;
#pragma unroll
      for (int g = 0; g < 4; ++g) {
        bn0[g] = *(const f32x4*)(p0 + g * (2 * NN * 4));
        bn1[g] = *(const f32x4*)(p1 + g * (2 * NN * 4));
      }
    }

    // ---- phase 1: C operands (bias + mterm) and both S-MFMA pairs ----
    f32x16 st0, st1;
    {
      f32x16 cc0, cc1;
#pragma unroll
      for (int g = 0; g < 4; ++g)
#pragma unroll
        for (int e = 0; e < 4; ++e) {
          const float mt = (&mt4[g].x)[e];
          cc0[g * 4 + e] = bc0[g][e] + mt;
          cc1[g * 4 + e] = bc1[g][e] + mt;
        }
      __builtin_amdgcn_s_setprio(1);
      st0 = __builtin_amdgcn_mfma_f32_32x32x16_bf16(ka0, qb[0][0], cc0, 0, 0, 0);
      st1 = __builtin_amdgcn_mfma_f32_32x32x16_bf16(ka0, qb[1][0], cc1, 0, 0, 0);
      st0 = __builtin_amdgcn_mfma_f32_32x32x16_bf16(ka1, qb[0][1], st0, 0, 0, 0);
      st1 = __builtin_amdgcn_mfma_f32_32x32x16_bf16(ka1, qb[1][1], st1, 0, 0, 0);
      __builtin_amdgcn_s_setprio(0);
    }

    // ---- phase 2: exp2 both chains (st0 first; st1 MFMA drains under it) --
#pragma unroll
    for (int r = 0; r < 16; ++r) st0[r] = __builtin_amdgcn_exp2f(st0[r]);
    {
      float s0 = (st0[0] + st0[1]) + (st0[2] + st0[3]);
      float s1 = (st0[4] + st0[5]) + (st0[6] + st0[7]);
      float s2 = (st0[8] + st0[9]) + (st0[10] + st0[11]);
      float s3 = (st0[12] + st0[13]) + (st0[14] + st0[15]);
      lsum0 += (s0 + s1) + (s2 + s3);
    }
#pragma unroll
    for (int r = 0; r < 16; ++r) st1[r] = __builtin_amdgcn_exp2f(st1[r]);
    {
      float s0 = (st1[0] + st1[1]) + (st1[2] + st1[3]);
      float s1 = (st1[4] + st1[5]) + (st1[6] + st1[7]);
      float s2 = (st1[8] + st1[9]) + (st1[10] + st1[11]);
      float s3 = (st1[12] + st1[13]) + (st1[14] + st1[15]);
      lsum1 += (s0 + s1) + (s2 + s3);
    }

    // ---- phase 3: pack+PV, chains interleaved (PV0 under pack1's VALU) ----
#pragma unroll
    for (int half = 0; half < 2; ++half) {
      const int b0 = half * 8;
      const bf16x8 va = half ? va1 : va0;
      // pack chain 0
      unsigned p00, p01, p02, p03;
      {
        unsigned A = cvt_pk_bf16(st0[b0 + 0], st0[b0 + 1]);
        unsigned B = cvt_pk_bf16(st0[b0 + 4], st0[b0 + 5]);
        asm volatile("v_permlane32_swap_b32 %0, %1" : "+v"(A), "+v"(B));
        p00 = A; p02 = B;
      }
      {
        unsigned A = cvt_pk_bf16(st0[b0 + 2], st0[b0 + 3]);
        unsigned B = cvt_pk_bf16(st0[b0 + 6], st0[b0 + 7]);
        asm volatile("v_permlane32_swap_b32 %0, %1" : "+v"(A), "+v"(B));
        p01 = A; p03 = B;
      }
      {
        u32x4 words = {p00, p01, p02, p03};
        const bf16x8 pf = __builtin_bit_cast(bf16x8, words);
        __builtin_amdgcn_s_setprio(1);
        ot0 = __builtin_amdgcn_mfma_f32_32x32x16_bf16(pf, va, ot0, 0, 0, 0);
        __builtin_amdgcn_s_setprio(0);
      }
      // pack chain 1 (VALU overlaps ot0's MFMA)
      unsigned p10, p11, p12, p13;
      {
        unsigned A = cvt_pk_bf16(st1[b0 + 0], st1[b0 + 1]);
        unsigned B = cvt_pk_bf16(st1[b0 + 4], st1[b0 + 5]);
        asm volatile("v_permlane32_swap_b32 %0, %1" : "+v"(A), "+v"(B));
        p10 = A; p12 = B;
      }
      {
        unsigned A = cvt_pk_bf16(st1[b0 + 2], st1[b0 + 3]);
        unsigned B = cvt_pk_bf16(st1[b0 + 6], st1[b0 + 7]);
        asm volatile("v_permlane32_swap_b32 %0, %1" : "+v"(A), "+v"(B));
        p11 = A; p13 = B;
      }
      {
        u32x4 words = {p10, p11, p12, p13};
        const bf16x8 pf = __builtin_bit_cast(bf16x8, words);
        __builtin_amdgcn_s_setprio(1);
        ot1 = __builtin_amdgcn_mfma_f32_32x32x16_bf16(pf, va, ot1, 0, 0, 0);
        __builtin_amdgcn_s_setprio(0);
      }
    }

    // rotate bias double-buffer
#pragma unroll
    for (int g = 0; g < 4; ++g) { bc0[g] = bn0[g]; bc1[g] = bn1[g]; }
  }

  // ---- denominators: lane-local + cross-half add, broadcast via LDS ----
  {
    const float l0 = lsum0 + __shfl_xor(lsum0, 32);
    const float l1 = lsum1 + __shfl_xor(lsum1, 32);
    Ls[rowbase + lo5] = 1.0f / l0;        // both halves write same value
    Ls[rowbase + 32 + lo5] = 1.0f / l1;
  }

  // ---- normalize + store (C-layout cols = d -> coalesced 128B segments) ----
#pragma unroll
  for (int r = 0; r < 16; ++r) {
    const int qp = (r & 3) + 8 * (r >> 2) + 4 * hi;
    const int q0 = rowbase + qp;
    const int q1 = rowbase + 32 + qp;
    out[((i * NN + q0) * HEADS + h) * DW + lo5] = ot0[r] * Ls[q0];
    out[((i * NN + q1) * HEADS + h) * DW + lo5] = ot1[r] * Ls[q1];
  }
}

extern "C" void kernel_launch(void* const* d_in, const int* in_sizes, int n_in,
                              void* d_out, int out_size, void* d_ws,
                              size_t ws_size, hipStream_t stream) {
  const float* x    = (const float*)d_in[0];
  const float* mask = (const float*)d_in[1];
  const float* Wq   = (const float*)d_in[2];
  const float* bq   = (const float*)d_in[3];
  const float* Wk   = (const float*)d_in[4];
  const float* bk   = (const float*)d_in[5];
  const float* Wv   = (const float*)d_in[6];
  const float* bv   = (const float*)d_in[7];
  const float* Wb   = (const float*)d_in[8];
  const float* bb   = (const float*)d_in[9];
  float* out = (float*)d_out;
  float* bias2 = (float*)d_ws;  // HEADS*8*4*2*256*4 floats = 1 MB

  bias_kernel<<<NN, 256, 0, stream>>>(x, Wb, bb, bias2);
  attn_mfma<<<NN * HEADS, 256, 0, stream>>>(x, mask, Wq, bq, Wk, bk, Wv, bv,
                                            bias2, out);
}